// Round 1
// baseline (221.389 us; speedup 1.0000x reference)
//
#include <hip/hip_runtime.h>
#include <hip/hip_bf16.h>

// Problem constants (fixed by setup_inputs)
constexpr int B = 4, Q = 100, C = 40, Cp1 = 41, HW = 65536;
constexpr int NPIX = B * HW;          // 262144

// B-part (MFMA one-hot GEMM): 7 q-tiles x 4 b = 28 rows, 128 K-segments of 512
constexpr int QT = 7;
constexpr int ROWS = B * QT;          // 28
constexpr int SEGS = 128;
constexpr int KSEG = HW / SEGS;       // 512
constexpr int BWAVES = ROWS * SEGS;   // 3584
constexpr int BBLK = BWAVES / 4;      // 896 blocks (4 waves each)

// A-part: 512 blocks, 256 thr, 2 px/thread (float2), 5-plane load batches
constexpr int ATHR = 256, APX = 2;
constexpr int ABLKS = NPIX / (ATHR * APX);   // 512
constexpr int ASLOT = HW / (ATHR * APX);     // 128
constexpr int QU = 5;

constexpr int GRID = BBLK + ABLKS;    // 1408 = 128 groups of 11 (4 A + 7 B)

// Workspace layout (4-byte words):
//  [0, 16000)        counts    u32 [B][Q][C]
//  [16000, 16160)    tsum      u32 [B][C]
//  [16160]           ce_sum    f32
//  [16161]           n_valid   u32
//  [16162, 32562)    inter_ext f32 [B*Q][41]   (col 40 = ignored-pixel sig sum)
constexpr int WS_WORDS = 32562;

typedef __attribute__((ext_vector_type(8))) short short8;   // 8 bf16
typedef __attribute__((ext_vector_type(4))) float f32x4;

__device__ __forceinline__ short f2bf(float f) {            // RNE f32->bf16
    unsigned u = __float_as_uint(f);
    u += 0x7FFF + ((u >> 16) & 1);
    return (short)(u >> 16);
}

__global__ void kZ(unsigned* __restrict__ ws, int n) {
    int i = blockIdx.x * blockDim.x + threadIdx.x;
    for (; i < n; i += gridDim.x * blockDim.x) ws[i] = 0u;
}

// ONE kernel, two independent phases. R12 change vs R11: phases are STRIPED
// through the block-index space (groups of 11 = 4 A-blocks + 7 B-blocks) so
// both are co-resident on every CU from t=0 — R11 dispatched all 896 B-blocks
// first, serializing the phases (t_A + t_B instead of max).
__global__ __launch_bounds__(256) void kBig(const float* __restrict__ masks,
                                            const int* __restrict__ targets,
                                            unsigned* __restrict__ counts,
                                            unsigned* __restrict__ tsum,
                                            float* __restrict__ ce_sum,
                                            unsigned* __restrict__ n_valid,
                                            float* __restrict__ inter_ext) {
    __shared__ float smem[4 * C];
    int tid = threadIdx.x;
    int blk = blockIdx.x;
    int lane = tid & 63, wave = tid >> 6;

    int grp = blk / 11, rem = blk - grp * 11;   // 128 groups x 11
    bool isA = rem < 4;

    if (!isA) {
        // ---------- B-part: MFMA one-hot GEMM (verified R11) ----------
        int bblk = grp * 7 + (rem - 4);  // 0..895
        int w = bblk * 4 + wave;         // 0..3583
        int row = w >> 7;                // /SEGS
        int seg = w & (SEGS - 1);
        int b = row / QT, qt = row - b * QT;
        int q0 = qt * 16;
        int k0 = seg * KSEG;
        int m = lane & 15, quad = lane >> 4;
        int qa = q0 + m; if (qa > 99) qa = 0;        // clamp (garbage rows unused)
        const float* ap = masks + ((size_t)b * Q + qa) * HW + k0 + quad * 8;
        const int*   tp = targets + (size_t)b * HW + k0 + quad * 8;
        int cv0 = m, cv1 = 16 + m;
        int cv2 = (m == 8) ? 255 : 32 + m;           // col 40 <- ignored pixels

        f32x4 acc0 = {0.f, 0.f, 0.f, 0.f};
        f32x4 acc1 = {0.f, 0.f, 0.f, 0.f};
        f32x4 acc2 = {0.f, 0.f, 0.f, 0.f};

        #pragma unroll 2
        for (int step = 0; step < KSEG / 32; ++step) {   // 16 steps
            int k = step * 32;
            float4 x0 = *(const float4*)(ap + k);
            float4 x1 = *(const float4*)(ap + k + 4);
            int4 t0 = *(const int4*)(tp + k);
            int4 t1 = *(const int4*)(tp + k + 4);
            float xs[8] = {x0.x, x0.y, x0.z, x0.w, x1.x, x1.y, x1.z, x1.w};
            int tss[8] = {t0.x, t0.y, t0.z, t0.w, t1.x, t1.y, t1.z, t1.w};
            short8 av, b0, b1, b2;
            #pragma unroll
            for (int j = 0; j < 8; ++j) {
                float sg = __builtin_amdgcn_rcpf(1.f + __expf(-xs[j]));
                av[j] = f2bf(sg);
                b0[j] = (tss[j] == cv0) ? (short)0x3F80 : (short)0;
                b1[j] = (tss[j] == cv1) ? (short)0x3F80 : (short)0;
                b2[j] = (tss[j] == cv2) ? (short)0x3F80 : (short)0;
            }
            acc0 = __builtin_amdgcn_mfma_f32_16x16x32_bf16(av, b0, acc0, 0, 0, 0);
            acc1 = __builtin_amdgcn_mfma_f32_16x16x32_bf16(av, b1, acc1, 0, 0, 0);
            acc2 = __builtin_amdgcn_mfma_f32_16x16x32_bf16(av, b2, acc2, 0, 0, 0);
        }

        // epilogue: D row = quad*4+reg, col = m (+ tile offset)
        #pragma unroll
        for (int reg = 0; reg < 4; ++reg) {
            int q = q0 + quad * 4 + reg;
            if (q < 100) {
                size_t base = (size_t)(b * Q + q) * Cp1;
                atomicAdd(&inter_ext[base + m], acc0[reg]);
                atomicAdd(&inter_ext[base + 16 + m], acc1[reg]);
                if (m <= 8) atomicAdd(&inter_ext[base + 32 + m], acc2[reg]);
            }
        }
    } else {
        // ---------- A-part: pixel-major (verified R8/R10/R11) ----------
        unsigned* ts_local = (unsigned*)&smem[0];
        float*    cred     = &smem[64];
        unsigned* vred     = (unsigned*)&smem[72];

        int ablk = grp * 4 + rem;        // 0..511
        int b = ablk / ASLOT;
        int hw = (ablk % ASLOT) * (ATHR * APX) + tid * APX;
        const float* mp = masks + (size_t)b * Q * HW + hw;
        int2 tg = *(const int2*)(targets + (size_t)b * HW + hw);
        int tgs[2] = {tg.x, tg.y};

        float m2[2] = {-INFINITY, -INFINITY}, s[2] = {0.f, 0.f}, xt[2] = {0.f, 0.f};
        int amax[2] = {0, 0};

        for (int qq = 0; qq < Q; qq += QU) {
            float2 vv[QU];
            #pragma unroll
            for (int u = 0; u < QU; ++u)
                vv[u] = *(const float2*)(mp + (size_t)(qq + u) * HW);
            #pragma unroll
            for (int u = 0; u < QU; ++u) {
                int q = qq + u;
                float v[2] = {vv[u].x, vv[u].y};
                #pragma unroll
                for (int j = 0; j < 2; ++j) {
                    s[j] += __expf(v[j]);                      // |v|<=~6: f32-safe
                    amax[j] = (v[j] > m2[j]) ? q : amax[j];    // strict >: first max
                    m2[j] = fmaxf(m2[j], v[j]);
                    xt[j] = (q == tgs[j]) ? v[j] : xt[j];
                }
            }
        }

        if (tid < C) ts_local[tid] = 0u;
        __syncthreads();

        float ce = 0.f;
        unsigned nv = 0;
        #pragma unroll
        for (int j = 0; j < 2; ++j) {
            if (tgs[j] != 255) {
                ce += __logf(s[j]) - xt[j];
                nv++;
                atomicAdd(&counts[((size_t)b * Q + amax[j]) * C + tgs[j]], 1u);
                atomicAdd(&ts_local[tgs[j]], 1u);
            }
        }
        for (int off = 32; off; off >>= 1) {
            ce += __shfl_xor(ce, off);
            nv += __shfl_xor(nv, off);
        }
        if (lane == 0) { cred[wave] = ce; vred[wave] = nv; }
        __syncthreads();
        if (tid == 0) {
            atomicAdd(ce_sum, cred[0] + cred[1] + cred[2] + cred[3]);
            atomicAdd(n_valid, vred[0] + vred[1] + vred[2] + vred[3]);
        }
        if (tid < C) {
            unsigned t = ts_local[tid];
            if (t) atomicAdd(&tsum[b * C + tid], t);
        }
    }
}

// Kernel C: finalize. src_sum derived from inter_ext's 41 columns. (Verified R11.)
__global__ __launch_bounds__(512) void kC(const float* __restrict__ logits,
                                          const unsigned* __restrict__ counts,
                                          const unsigned* __restrict__ tsum,
                                          const float* __restrict__ inter_ext,
                                          const float* __restrict__ ce_sum,
                                          const unsigned* __restrict__ n_valid,
                                          float* __restrict__ out) {
    int tid = threadIdx.x;
    __shared__ float dice_sum[C];
    __shared__ float ssum[B * Q];
    __shared__ float wred[8];
    __shared__ float s_lce;
    if (tid < C) dice_sum[tid] = 0.f;
    if (tid < B * Q) {                     // src_sum[bq] = sum of all 41 cols
        const float* r = inter_ext + (size_t)tid * Cp1;
        float t = 0.f;
        #pragma unroll
        for (int c = 0; c < Cp1; ++c) t += r[c];
        ssum[tid] = t;
    }

    float ce_acc = 0.f;
    for (int i = tid; i < B * Q; i += 512) {
        const unsigned* cnt = counts + (size_t)i * C;
        unsigned best = 0;
        int tc = C;
        #pragma unroll
        for (int c = 0; c < C; ++c) {
            unsigned v = cnt[c];
            if (v > best) { best = v; tc = c; }
        }
        if (tc != C) {
            const float* lg = logits + (size_t)i * Cp1;
            float mm = -INFINITY, xt = 0.f;
            #pragma unroll
            for (int c = 0; c < Cp1; ++c) {
                float v = lg[c];
                mm = fmaxf(mm, v);
                if (c == tc) xt = v;
            }
            float ss = 0.f;
            #pragma unroll
            for (int c = 0; c < Cp1; ++c) ss += __expf(lg[c] - mm);
            float nll = mm + __logf(ss) - xt;
            float p = __expf(-nll);
            float om = 1.f - p;
            ce_acc += om * om * nll;
        }
    }
    for (int off = 32; off; off >>= 1) ce_acc += __shfl_xor(ce_acc, off);
    if ((tid & 63) == 0) wred[tid >> 6] = ce_acc;
    __syncthreads();                        // also publishes ssum + dice_sum init
    if (tid == 0) {
        float t = 0.f;
        for (int w = 0; w < 8; ++w) t += wred[w];
        s_lce = t;
    }

    for (int i = tid; i < B * Q * C; i += 512) {
        int bq = i / C, c = i - bq * C;
        float denom = ssum[bq] + (float)tsum[(bq / Q) * C + c] + 1e-8f;
        atomicAdd(&dice_sum[c], 2.f * inter_ext[(size_t)bq * Cp1 + c] / denom);
    }
    __syncthreads();

    if (tid == 0) {
        float dl = 0.f;
        for (int c = 0; c < C; ++c) {
            unsigned ts = tsum[c] + tsum[C + c] + tsum[2 * C + c] + tsum[3 * C + c];
            if (ts > 0) dl += 1.f - dice_sum[c] * (1.f / (B * Q));
        }
        dl *= (1.f / C);
        float ce_mask = ce_sum[0] / fmaxf((float)n_valid[0], 1.f);
        float lce = s_lce * (1.f / (B * Q));
        out[0] = 2.f * lce + 5.f * ce_mask + 5.f * dl;
    }
}

extern "C" void kernel_launch(void* const* d_in, const int* in_sizes, int n_in,
                              void* d_out, int out_size, void* d_ws, size_t ws_size,
                              hipStream_t stream) {
    const float* logits  = (const float*)d_in[0];   // [B,Q,41] f32
    const float* masks   = (const float*)d_in[1];   // [B,Q,H,W] f32
    const int*   targets = (const int*)d_in[2];     // [B,H,W] int32
    float* out = (float*)d_out;                     // f32 scalar

    unsigned* ws        = (unsigned*)d_ws;
    unsigned* counts    = ws;                       // 16000 u32
    unsigned* tsum      = ws + 16000;               // 160 u32
    float*    ce_sum    = (float*)(ws + 16160);     // 1 f32
    unsigned* n_valid   = ws + 16161;               // 1 u32
    float*    inter_ext = (float*)(ws + 16162);     // 16400 f32

    kZ<<<64, 256, 0, stream>>>(ws, WS_WORDS);
    kBig<<<GRID, 256, 0, stream>>>(masks, targets, counts, tsum, ce_sum, n_valid,
                                   inter_ext);
    kC<<<1, 512, 0, stream>>>(logits, counts, tsum, inter_ext, ce_sum, n_valid, out);
}

// Round 2
// 220.691 us; speedup vs baseline: 1.0032x; 1.0032x over previous
//
#include <hip/hip_runtime.h>

// Problem constants (fixed by setup_inputs)
constexpr int B = 4, Q = 100, C = 40, Cp1 = 41, HW = 65536;

// Fused kernel: 512 blocks (4 b x 128 segments of 512 px), 256 threads (4 waves).
// Each block makes ONE pass over its masks slice:
//   - per-thread online softmax over q (identical math/order to verified A-part)
//   - per-q-tile LDS bf16 sigmoid tile -> one-hot MFMA (identical chain to
//     verified B-part: same k-order, same 512-px segment grouping)
constexpr int FBLKS = 512;

// Workspace layout (4-byte words):
//  [0, 16000)        counts    u32 [B][Q][C]
//  [16000, 16160)    tsum      u32 [B][C]
//  [16160]           ce_sum    f32
//  [16161]           n_valid   u32
//  [16162, 32562)    inter_ext f32 [B*Q][41]   (col 40 = ignored-pixel sig sum)
constexpr int WS_WORDS = 32562;

typedef __attribute__((ext_vector_type(8))) short short8;   // 8 bf16
typedef __attribute__((ext_vector_type(4))) float f32x4;

__device__ __forceinline__ short f2bf(float f) {            // RNE f32->bf16
    unsigned u = __float_as_uint(f);
    u += 0x7FFF + ((u >> 16) & 1);
    return (short)(u >> 16);
}

__global__ void kZ(unsigned* __restrict__ ws, int n) {
    int i = blockIdx.x * blockDim.x + threadIdx.x;
    for (; i < n; i += gridDim.x * blockDim.x) ws[i] = 0u;
}

__global__ __launch_bounds__(256) void kF(const float* __restrict__ masks,
                                          const int* __restrict__ targets,
                                          unsigned* __restrict__ counts,
                                          unsigned* __restrict__ tsum,
                                          float* __restrict__ ce_sum,
                                          unsigned* __restrict__ n_valid,
                                          float* __restrict__ inter_ext) {
    // LDS: sigmoid tile [16 q][512 px] bf16, XOR-swizzled (byte ^= (row&7)<<4)
    // so MFMA A-frag ds_read_b128 (row stride 1024B) is 2-way (free) not 16-way.
    __shared__ __align__(16) short tileS[16 * 512];          // 16 KiB
    __shared__ __align__(8) unsigned char tgt8[512];         // block's targets
    __shared__ float smem[160];   // ts_local[0..39], cred[64..67], vred[72..75]

    const int tid = threadIdx.x;
    const int l = tid & 63, w = tid >> 6;
    const int m = l & 15, quad = l >> 4;

    const int blk = blockIdx.x;
    const int b = blk >> 7;                 // 0..3
    const int seg = blk & 127;              // 0..127
    const int pxb = w * 128 + 2 * l;        // px within block [0,512)
    const int p0 = seg * 512 + pxb;         // px within image

    // ---- prologue: targets once, broadcast via LDS bytes ----
    const int2 tg = *(const int2*)(targets + (size_t)b * HW + p0);
    *(unsigned short*)&tgt8[pxb] =
        (unsigned short)((tg.x & 255) | ((tg.y & 255) << 8));
    unsigned* ts_local = (unsigned*)&smem[0];
    if (tid < C) ts_local[tid] = 0u;
    __syncthreads();

    const float* mp = masks + (size_t)b * Q * HW + p0;
    const int tg0 = tg.x, tg1 = tg.y;

    // per-pixel softmax state (2 px/thread) — formulas/order == verified A-part
    float m20 = -INFINITY, m21 = -INFINITY;
    float s0 = 0.f, s1 = 0.f, xt0 = 0.f, xt1 = 0.f;
    int am0 = 0, am1 = 0;

    char* tbytes = (char*)tileS;
    const int wbase = w * 256 + l * 4;      // my px-pair byte offset within a row

    // wave MFMA role: w0 -> cols 0-15, w1 -> 16-31, w2 -> 32-40, w3 -> none
    const int colbase = w * 16;
    const int cv = (w == 2) ? ((m == 8) ? 255 : 32 + m) : (colbase + m);

    for (int qt = 0; qt < 7; ++qt) {
        const int nu = (qt == 6) ? 4 : 16;      // q-tile 6 covers q 96..99 only

        // ---- load phase: up to 16 float2 in flight per thread ----
        float2 vv[16];
        const float* mq = mp + (size_t)(qt * 16) * HW;
        #pragma unroll
        for (int u = 0; u < 16; ++u)
            if (u < nu) vv[u] = *(const float2*)(mq + (size_t)u * HW);

        // ---- process: softmax state + sigmoid->bf16 tile write ----
        #pragma unroll
        for (int u = 0; u < 16; ++u)
            if (u < nu) {
                const int q = qt * 16 + u;
                const float v0 = vv[u].x, v1 = vv[u].y;
                s0 += __expf(v0);
                s1 += __expf(v1);
                am0 = (v0 > m20) ? q : am0;  m20 = fmaxf(m20, v0);
                am1 = (v1 > m21) ? q : am1;  m21 = fmaxf(m21, v1);
                xt0 = (q == tg0) ? v0 : xt0;
                xt1 = (q == tg1) ? v1 : xt1;
                const float g0 = __builtin_amdgcn_rcpf(1.f + __expf(-v0));
                const float g1 = __builtin_amdgcn_rcpf(1.f + __expf(-v1));
                const unsigned pk = (unsigned)(unsigned short)f2bf(g0) |
                                    ((unsigned)(unsigned short)f2bf(g1) << 16);
                *(unsigned*)(tbytes + ((u * 1024 + wbase) ^ ((u & 7) << 4))) = pk;
            }

        // publish tile: wait own ds_writes only (vm loads may stay in flight),
        // raw barrier (no vmcnt(0) drain), compiler fences pin LDS op order.
        asm volatile("s_waitcnt lgkmcnt(0)" ::: "memory");
        __builtin_amdgcn_s_barrier();
        asm volatile("" ::: "memory");

        // ---- MFMA phase: one-hot GEMM, identical chain to verified B-part ----
        f32x4 acc = {0.f, 0.f, 0.f, 0.f};
        if (w < 3) {
            #pragma unroll
            for (int kc = 0; kc < 16; ++kc) {
                const short8 av = *(const short8*)(tbytes +
                    ((m * 1024 + kc * 64 + quad * 16) ^ ((m & 7) << 4)));
                const unsigned long long tw =
                    *(const unsigned long long*)&tgt8[kc * 32 + quad * 8];
                short8 bv;
                #pragma unroll
                for (int j = 0; j < 8; ++j) {
                    const int tb = (int)((tw >> (8 * j)) & 255);
                    bv[j] = (tb == cv) ? (short)0x3F80 : (short)0;
                }
                acc = __builtin_amdgcn_mfma_f32_16x16x32_bf16(av, bv, acc, 0, 0, 0);
            }
        }
        asm volatile("" ::: "memory");
        __builtin_amdgcn_s_barrier();
        asm volatile("" ::: "memory");

        // epilogue after barrier (regs only): D row = quad*4+reg, col = m
        if (w < 3 && !(w == 2 && m > 8)) {
            #pragma unroll
            for (int reg = 0; reg < 4; ++reg) {
                const int q = qt * 16 + quad * 4 + reg;
                if (q < 100)    // qt=6 rows 4..15 hold stale tile data: skipped
                    atomicAdd(&inter_ext[(size_t)(b * Q + q) * Cp1 + colbase + m],
                              acc[reg]);
            }
        }
    }

    // ---- softmax epilogue (identical to verified A-part) ----
    float ce = 0.f;
    unsigned nv = 0u;
    if (tg0 != 255) {
        ce += __logf(s0) - xt0; nv++;
        atomicAdd(&counts[((size_t)b * Q + am0) * C + tg0], 1u);
        atomicAdd(&ts_local[tg0], 1u);
    }
    if (tg1 != 255) {
        ce += __logf(s1) - xt1; nv++;
        atomicAdd(&counts[((size_t)b * Q + am1) * C + tg1], 1u);
        atomicAdd(&ts_local[tg1], 1u);
    }
    for (int off = 32; off; off >>= 1) {
        ce += __shfl_xor(ce, off);
        nv += __shfl_xor(nv, off);
    }
    float* cred = &smem[64];
    unsigned* vred = (unsigned*)&smem[72];
    if (l == 0) { cred[w] = ce; vred[w] = nv; }
    __syncthreads();
    if (tid == 0) {
        atomicAdd(ce_sum, cred[0] + cred[1] + cred[2] + cred[3]);
        atomicAdd(n_valid, vred[0] + vred[1] + vred[2] + vred[3]);
    }
    if (tid < C) {
        unsigned t = ts_local[tid];
        if (t) atomicAdd(&tsum[b * C + tid], t);
    }
}

// Kernel C: finalize. src_sum derived from inter_ext's 41 columns. (Verified R11.)
__global__ __launch_bounds__(512) void kC(const float* __restrict__ logits,
                                          const unsigned* __restrict__ counts,
                                          const unsigned* __restrict__ tsum,
                                          const float* __restrict__ inter_ext,
                                          const float* __restrict__ ce_sum,
                                          const unsigned* __restrict__ n_valid,
                                          float* __restrict__ out) {
    int tid = threadIdx.x;
    __shared__ float dice_sum[C];
    __shared__ float ssum[B * Q];
    __shared__ float wred[8];
    __shared__ float s_lce;
    if (tid < C) dice_sum[tid] = 0.f;
    if (tid < B * Q) {                     // src_sum[bq] = sum of all 41 cols
        const float* r = inter_ext + (size_t)tid * Cp1;
        float t = 0.f;
        #pragma unroll
        for (int c = 0; c < Cp1; ++c) t += r[c];
        ssum[tid] = t;
    }

    float ce_acc = 0.f;
    for (int i = tid; i < B * Q; i += 512) {
        const unsigned* cnt = counts + (size_t)i * C;
        unsigned best = 0;
        int tc = C;
        #pragma unroll
        for (int c = 0; c < C; ++c) {
            unsigned v = cnt[c];
            if (v > best) { best = v; tc = c; }
        }
        if (tc != C) {
            const float* lg = logits + (size_t)i * Cp1;
            float mm = -INFINITY, xt = 0.f;
            #pragma unroll
            for (int c = 0; c < Cp1; ++c) {
                float v = lg[c];
                mm = fmaxf(mm, v);
                if (c == tc) xt = v;
            }
            float ss = 0.f;
            #pragma unroll
            for (int c = 0; c < Cp1; ++c) ss += __expf(lg[c] - mm);
            float nll = mm + __logf(ss) - xt;
            float p = __expf(-nll);
            float om = 1.f - p;
            ce_acc += om * om * nll;
        }
    }
    for (int off = 32; off; off >>= 1) ce_acc += __shfl_xor(ce_acc, off);
    if ((tid & 63) == 0) wred[tid >> 6] = ce_acc;
    __syncthreads();                        // also publishes ssum + dice_sum init
    if (tid == 0) {
        float t = 0.f;
        for (int w = 0; w < 8; ++w) t += wred[w];
        s_lce = t;
    }

    for (int i = tid; i < B * Q * C; i += 512) {
        int bq = i / C, c = i - bq * C;
        float denom = ssum[bq] + (float)tsum[(bq / Q) * C + c] + 1e-8f;
        atomicAdd(&dice_sum[c], 2.f * inter_ext[(size_t)bq * Cp1 + c] / denom);
    }
    __syncthreads();

    if (tid == 0) {
        float dl = 0.f;
        for (int c = 0; c < C; ++c) {
            unsigned ts = tsum[c] + tsum[C + c] + tsum[2 * C + c] + tsum[3 * C + c];
            if (ts > 0) dl += 1.f - dice_sum[c] * (1.f / (B * Q));
        }
        dl *= (1.f / C);
        float ce_mask = ce_sum[0] / fmaxf((float)n_valid[0], 1.f);
        float lce = s_lce * (1.f / (B * Q));
        out[0] = 2.f * lce + 5.f * ce_mask + 5.f * dl;
    }
}

extern "C" void kernel_launch(void* const* d_in, const int* in_sizes, int n_in,
                              void* d_out, int out_size, void* d_ws, size_t ws_size,
                              hipStream_t stream) {
    const float* logits  = (const float*)d_in[0];   // [B,Q,41] f32
    const float* masks   = (const float*)d_in[1];   // [B,Q,H,W] f32
    const int*   targets = (const int*)d_in[2];     // [B,H,W] int32
    float* out = (float*)d_out;                     // f32 scalar

    unsigned* ws        = (unsigned*)d_ws;
    unsigned* counts    = ws;                       // 16000 u32
    unsigned* tsum      = ws + 16000;               // 160 u32
    float*    ce_sum    = (float*)(ws + 16160);     // 1 f32
    unsigned* n_valid   = ws + 16161;               // 1 u32
    float*    inter_ext = (float*)(ws + 16162);     // 16400 f32

    kZ<<<64, 256, 0, stream>>>(ws, WS_WORDS);
    kF<<<FBLKS, 256, 0, stream>>>(masks, targets, counts, tsum, ce_sum, n_valid,
                                  inter_ext);
    kC<<<1, 512, 0, stream>>>(logits, counts, tsum, inter_ext, ce_sum, n_valid, out);
}